// Round 7
// baseline (1770.476 us; speedup 1.0000x reference)
//
#include <hip/hip_runtime.h>
#include <stdint.h>
#include <math.h>

#define NN 8192
#define DIM 64
#define KSEL 32
#define BK2 16
#define TILE 128
#define NTB (NN / TILE)          // 64 tiles per side
#define NTRI ((NTB * (NTB + 1)) / 2)   // 2080 upper-tri blocks

// ---- XLA/Eigen f32 tanh rational approximation (bit-exact emulation) ----
__device__ __forceinline__ float tanh_xla(float x) {
    const float kClamp = 7.90531110763549805f;
    float xc = fminf(fmaxf(x, -kClamp), kClamp);
    float x2 = xc * xc;
    float p = -2.76076847742355e-16f;
    p = fmaf(x2, p, 2.00018790482477e-13f);
    p = fmaf(x2, p, -8.60467152213735e-11f);
    p = fmaf(x2, p, 5.12229709037114e-08f);
    p = fmaf(x2, p, 1.48572235717979e-05f);
    p = fmaf(x2, p, 6.37261928875436e-04f);
    p = fmaf(x2, p, 4.89352455891786e-03f);
    p = xc * p;
    float q = 1.19825839466702e-06f;
    q = fmaf(x2, q, 1.18534705686654e-04f);
    q = fmaf(x2, q, 2.26843463243900e-03f);
    q = fmaf(x2, q, 4.89352518554385e-03f);
    float r = p / q;
    return (fabsf(x) < 0.0004f) ? x : r;
}
// positive-input variant (ax >= 0), same bits as tanh_xla(ax)
__device__ __forceinline__ float tanh_xla_pos(float ax) {
    const float kClamp = 7.90531110763549805f;
    float xc = fminf(ax, kClamp);
    float x2 = xc * xc;
    float p = -2.76076847742355e-16f;
    p = fmaf(x2, p, 2.00018790482477e-13f);
    p = fmaf(x2, p, -8.60467152213735e-11f);
    p = fmaf(x2, p, 5.12229709037114e-08f);
    p = fmaf(x2, p, 1.48572235717979e-05f);
    p = fmaf(x2, p, 6.37261928875436e-04f);
    p = fmaf(x2, p, 4.89352455891786e-03f);
    p = xc * p;
    float q = 1.19825839466702e-06f;
    q = fmaf(x2, q, 1.18534705686654e-04f);
    q = fmaf(x2, q, 2.26843463243900e-03f);
    q = fmaf(x2, q, 4.89352518554385e-03f);
    float r = p / q;
    return (ax < 0.0004f) ? ax : r;
}

// ---- kernel 1: V = tanh_xla(3*(E[idx] @ W.T + b)) in f32, XLA order ----
__global__ __launch_bounds__(256) void k_embed(
    const int* __restrict__ gidx,
    const float* __restrict__ E1, const float* __restrict__ E2,
    const float* __restrict__ W1, const float* __restrict__ b1,
    const float* __restrict__ W2, const float* __restrict__ b2,
    float* __restrict__ V1, float* __restrict__ V2)
{
    __shared__ float W1s[DIM][DIM + 1];
    __shared__ float W2s[DIM][DIM + 1];
    __shared__ float E1s[4][DIM];
    __shared__ float E2s[4][DIM];
    const int t = threadIdx.x;
    for (int i = t; i < DIM * DIM; i += 256) {
        W1s[i >> 6][i & 63] = W1[i];
        W2s[i >> 6][i & 63] = W2[i];
    }
    const int rbase = blockIdx.x * 4;
    for (int i = t; i < 4 * DIM; i += 256) {
        const int r = i >> 6, k = i & 63;
        const int g = gidx[rbase + r];
        E1s[r][k] = E1[(size_t)g * DIM + k];
        E2s[r][k] = E2[(size_t)g * DIM + k];
    }
    __syncthreads();
    const int o = t & 63, rs = t >> 6;
    float m1 = 0.0f, m2 = 0.0f;
    #pragma unroll
    for (int k = 0; k < DIM; ++k) {
        m1 = fmaf(E1s[rs][k], W1s[o][k], m1);
        m2 = fmaf(E2s[rs][k], W2s[o][k], m2);
    }
    V1[(size_t)(rbase + rs) * DIM + o] = tanh_xla(3.0f * (m1 + b1[o]));
    V2[(size_t)(rbase + rs) * DIM + o] = tanh_xla(3.0f * (m2 + b2[o]));
}

// ---- kernel 2: A = relu(tanh_xla(3*(M1 - M2))), bit-exact XLA chains. ----
// 1D triangular grid; BK2=16 -> 32 KB LDS -> 4 blocks/CU (16 waves/CU).
__global__ __launch_bounds__(256, 4) void k_score(
    const float* __restrict__ V1, const float* __restrict__ V2,
    float* __restrict__ out)
{
    // decode upper-tri linear id -> (bi, bj), bi <= bj
    // base(r) = 64r - r(r-1)/2
    const int L = blockIdx.x;
    int bi = (int)(64.5f - sqrtf(fmaf(-2.0f, (float)L, 64.5f * 64.5f)));
    while (bi * NTB - (bi * (bi - 1)) / 2 > L) --bi;
    while ((bi + 1) * NTB - ((bi + 1) * bi) / 2 <= L) ++bi;
    const int bj = bi + (L - (bi * NTB - (bi * (bi - 1)) / 2));

    __shared__ float sA1[BK2][TILE];           // V1 rows I, k-major
    __shared__ float sA2[BK2][TILE];           // V2 rows I
    __shared__ float sB1[BK2][TILE];           // V1 rows J
    __shared__ float sB2[BK2][TILE];           // V2 rows J

    const int t = threadIdx.x;
    const int tx = t & 15;                     // 8 cols each
    const int ty = t >> 4;                     // 8 rows each
    const int Ibase = bi * TILE, Jbase = bj * TILE;

    float acc1[8][8], acc2[8][8];
    #pragma unroll
    for (int i = 0; i < 8; ++i)
        #pragma unroll
        for (int j = 0; j < 8; ++j) { acc1[i][j] = 0.0f; acc2[i][j] = 0.0f; }

    for (int ck = 0; ck < DIM; ck += BK2) {    // ascending k chunks
        __syncthreads();
        #pragma unroll
        for (int it = 0; it < 2; ++it) {       // stage transposed, r = lane-fast
            const int idx = it * 256 + t;      // 0..511
            const int r   = idx & 127;
            const int c4  = idx >> 7;          // 0..3
            float4 f;
            f = *(const float4*)&V1[(size_t)(Ibase + r) * DIM + ck + c4 * 4];
            sA1[c4*4+0][r]=f.x; sA1[c4*4+1][r]=f.y; sA1[c4*4+2][r]=f.z; sA1[c4*4+3][r]=f.w;
            f = *(const float4*)&V2[(size_t)(Ibase + r) * DIM + ck + c4 * 4];
            sA2[c4*4+0][r]=f.x; sA2[c4*4+1][r]=f.y; sA2[c4*4+2][r]=f.z; sA2[c4*4+3][r]=f.w;
            f = *(const float4*)&V1[(size_t)(Jbase + r) * DIM + ck + c4 * 4];
            sB1[c4*4+0][r]=f.x; sB1[c4*4+1][r]=f.y; sB1[c4*4+2][r]=f.z; sB1[c4*4+3][r]=f.w;
            f = *(const float4*)&V2[(size_t)(Jbase + r) * DIM + ck + c4 * 4];
            sB2[c4*4+0][r]=f.x; sB2[c4*4+1][r]=f.y; sB2[c4*4+2][r]=f.z; sB2[c4*4+3][r]=f.w;
        }
        __syncthreads();
        #pragma unroll 2
        for (int k = 0; k < BK2; ++k) {        // strictly ascending k
            float a1[8], a2[8], c1[8], c2[8];
            *(float4*)&a1[0] = *(const float4*)&sA1[k][ty * 8];
            *(float4*)&a1[4] = *(const float4*)&sA1[k][ty * 8 + 4];
            *(float4*)&a2[0] = *(const float4*)&sA2[k][ty * 8];
            *(float4*)&a2[4] = *(const float4*)&sA2[k][ty * 8 + 4];
            *(float4*)&c1[0] = *(const float4*)&sB1[k][tx * 8];
            *(float4*)&c1[4] = *(const float4*)&sB1[k][tx * 8 + 4];
            *(float4*)&c2[0] = *(const float4*)&sB2[k][tx * 8];
            *(float4*)&c2[4] = *(const float4*)&sB2[k][tx * 8 + 4];
            #pragma unroll
            for (int i = 0; i < 8; ++i)
                #pragma unroll
                for (int j = 0; j < 8; ++j) {
                    acc1[i][j] = fmaf(a1[i], c2[j], acc1[i][j]);  // M1: v1_i.v2_j
                    acc2[i][j] = fmaf(a2[i], c1[j], acc2[i][j]);  // M2: v2_i.v1_j
                }
        }
    }
    // epilogue in-place: acc1 <- wn (normal), acc2 <- wm (mirror)
    #pragma unroll
    for (int i = 0; i < 8; ++i)
        #pragma unroll
        for (int j = 0; j < 8; ++j) {
            const float aa = acc1[i][j] - acc2[i][j];   // one f32 sub (M1-M2)
            const float tt = tanh_xla_pos(3.0f * fabsf(aa));
            acc1[i][j] = (aa > 0.0f) ? tt : 0.0f;       // relu(tanh(3a))
            acc2[i][j] = (aa < 0.0f) ? tt : 0.0f;       // relu(tanh(-3a))
        }
    #pragma unroll
    for (int i = 0; i < 8; ++i) {
        const int gi = Ibase + ty * 8 + i;
        float4* p = (float4*)&out[(size_t)gi * NN + Jbase + tx * 8];
        p[0] = make_float4(acc1[i][0], acc1[i][1], acc1[i][2], acc1[i][3]);
        p[1] = make_float4(acc1[i][4], acc1[i][5], acc1[i][6], acc1[i][7]);
    }
    if (bi != bj) {
        #pragma unroll
        for (int j = 0; j < 8; ++j) {
            const int gj = Jbase + tx * 8 + j;
            float4* p = (float4*)&out[(size_t)gj * NN + Ibase + ty * 8];
            p[0] = make_float4(acc2[0][j], acc2[1][j], acc2[2][j], acc2[3][j]);
            p[1] = make_float4(acc2[4][j], acc2[5][j], acc2[6][j], acc2[7][j]);
        }
    }
}

// ---- kernel 3: exact stable top-32 per row, 44-bit radix select ----
// key = (A_bits << 13) | (8191 - col). Uniform early-break when resolved.
__global__ __launch_bounds__(256) void k_topk(float* __restrict__ out)
{
    __shared__ uint32_t hist[4][2048];
    __shared__ uint32_t waveTot[4];
    __shared__ uint32_t bc_bin, bc_ca, bc_m, bc_flag;

    const int row = blockIdx.x;
    const int t = threadIdx.x;
    const int wid = t >> 6, lane = t & 63;
    float* rp = out + (size_t)row * NN;

    float v[32];
    #pragma unroll
    for (int s = 0; s < 8; ++s) {
        const float4 f = *(const float4*)&rp[(s * 256 + t) * 4];
        v[s*4+0] = f.x; v[s*4+1] = f.y; v[s*4+2] = f.z; v[s*4+3] = f.w;
    }
    if (t == 0) bc_flag = 0;

    uint64_t prefix = 0, thr = 0;
    int need = KSEL;
    bool done = false;   // block-uniform at all times

    for (int pass = 0; pass < 4; ++pass) {
        const int shift = 33 - 11 * pass;
        {   // zero hist: 2048 uint4 / 256 thr = 8 each
            const uint4 z = make_uint4(0u, 0u, 0u, 0u);
            uint4* hp = (uint4*)hist;
            #pragma unroll
            for (int i = 0; i < 8; ++i) hp[i * 256 + t] = z;
        }
        __syncthreads();
        #pragma unroll
        for (int s = 0; s < 8; ++s) {
            #pragma unroll
            for (int e = 0; e < 4; ++e) {
                const uint32_t vb = __float_as_uint(v[s*4+e]);
                if (vb == 0u) continue;
                const int gi = s * 1024 + t * 4 + e;
                const uint64_t key = ((uint64_t)vb << 13) | (uint32_t)(8191 - gi);
                if ((key >> (shift + 11)) == prefix)
                    atomicAdd(&hist[wid][(uint32_t)((key >> shift) & 2047u)], 1u);
            }
        }
        __syncthreads();
        uint32_t m[8]; uint32_t tot = 0;
        #pragma unroll
        for (int i = 0; i < 8; ++i) {
            const int b = t * 8 + i;
            m[i] = hist[0][b] + hist[1][b] + hist[2][b] + hist[3][b];
            tot += m[i];
        }
        uint32_t ssum = tot;   // inclusive suffix-sum within wave
        #pragma unroll
        for (int d = 1; d < 64; d <<= 1) {
            const uint32_t o = __shfl_down(ssum, d, 64);
            if (lane + d < 64) ssum += o;
        }
        if (lane == 0) waveTot[wid] = ssum;
        __syncthreads();
        {
            uint32_t above = 0;
            for (int w2 = wid + 1; w2 < 4; ++w2) above += waveTot[w2];
            if (pass == 0) {
                const uint32_t totalAll = waveTot[0] + waveTot[1] + waveTot[2] + waveTot[3];
                if (totalAll < (uint32_t)need && t == 0) bc_flag = 1;  // <32 positives
            }
            uint32_t c = (ssum - tot) + above;       // count in bins above my chunk
            #pragma unroll
            for (int i = 7; i >= 0; --i) {           // walk my 8 bins top-down
                if (c < (uint32_t)need && (uint32_t)need <= c + m[i]) {
                    bc_bin = (uint32_t)(t * 8 + i);  // unique winner
                    bc_ca  = c;
                    bc_m   = m[i];
                }
                c += m[i];
            }
        }
        __syncthreads();
        if (bc_flag) { thr = 1; done = true; }       // keep all positives
        else {
            prefix = (prefix << 11) | (uint64_t)bc_bin;
            need  -= (int)bc_ca;
            if ((uint32_t)need == bc_m) {            // whole bin selected exactly
                thr = prefix << shift;               // bin lower bound
                done = true;
            } else if (pass == 3) { thr = prefix; done = true; }
        }
        if (done) break;                              // block-uniform
        __syncthreads();
    }

    #pragma unroll
    for (int s = 0; s < 8; ++s) {
        float w[4];
        #pragma unroll
        for (int e = 0; e < 4; ++e) {
            const float a = v[s*4+e];
            const uint32_t vb = __float_as_uint(a);
            const int gi = s * 1024 + t * 4 + e;
            const uint64_t key = ((uint64_t)vb << 13) | (uint32_t)(8191 - gi);
            w[e] = (vb != 0u && key >= thr) ? a : 0.f;
        }
        *(float4*)&rp[(s * 256 + t) * 4] = make_float4(w[0], w[1], w[2], w[3]);
    }
}

extern "C" void kernel_launch(void* const* d_in, const int* in_sizes, int n_in,
                              void* d_out, int out_size, void* d_ws, size_t ws_size,
                              hipStream_t stream)
{
    const int*   idx = (const int*)  d_in[0];
    const float* E1  = (const float*)d_in[1];
    const float* E2  = (const float*)d_in[2];
    const float* W1  = (const float*)d_in[3];
    const float* b1  = (const float*)d_in[4];
    const float* W2  = (const float*)d_in[5];
    const float* b2  = (const float*)d_in[6];
    float* out = (float*)d_out;
    float* V1 = (float*)d_ws;                 // 2 MB
    float* V2 = V1 + (size_t)NN * DIM;        // 2 MB

    k_embed<<<NN / 4, 256, 0, stream>>>(idx, E1, E2, W1, b1, W2, b2, V1, V2);
    k_score<<<NTRI, 256, 0, stream>>>(V1, V2, out);
    k_topk<<<NN, 256, 0, stream>>>(out);
}

// Round 8
// 300.847 us; speedup vs baseline: 5.8850x; 5.8850x over previous
//
#include <hip/hip_runtime.h>
#include <stdint.h>
#include <math.h>

#define NN 8192
#define DIM 64
#define KSEL 32
#define BK2 16
#define TILE 128
#define NTB (NN / TILE)          // 64 tiles per side
#define NTRI ((NTB * (NTB + 1)) / 2)   // 2080 upper-tri blocks

// ---- XLA/Eigen f32 tanh rational approximation (bit-exact emulation) ----
__device__ __forceinline__ float tanh_xla(float x) {
    const float kClamp = 7.90531110763549805f;
    float xc = fminf(fmaxf(x, -kClamp), kClamp);
    float x2 = xc * xc;
    float p = -2.76076847742355e-16f;
    p = fmaf(x2, p, 2.00018790482477e-13f);
    p = fmaf(x2, p, -8.60467152213735e-11f);
    p = fmaf(x2, p, 5.12229709037114e-08f);
    p = fmaf(x2, p, 1.48572235717979e-05f);
    p = fmaf(x2, p, 6.37261928875436e-04f);
    p = fmaf(x2, p, 4.89352455891786e-03f);
    p = xc * p;
    float q = 1.19825839466702e-06f;
    q = fmaf(x2, q, 1.18534705686654e-04f);
    q = fmaf(x2, q, 2.26843463243900e-03f);
    q = fmaf(x2, q, 4.89352518554385e-03f);
    float r = p / q;
    return (fabsf(x) < 0.0004f) ? x : r;
}
// positive-input variant (ax >= 0), same bits as tanh_xla(ax)
__device__ __forceinline__ float tanh_xla_pos(float ax) {
    const float kClamp = 7.90531110763549805f;
    float xc = fminf(ax, kClamp);
    float x2 = xc * xc;
    float p = -2.76076847742355e-16f;
    p = fmaf(x2, p, 2.00018790482477e-13f);
    p = fmaf(x2, p, -8.60467152213735e-11f);
    p = fmaf(x2, p, 5.12229709037114e-08f);
    p = fmaf(x2, p, 1.48572235717979e-05f);
    p = fmaf(x2, p, 6.37261928875436e-04f);
    p = fmaf(x2, p, 4.89352455891786e-03f);
    p = xc * p;
    float q = 1.19825839466702e-06f;
    q = fmaf(x2, q, 1.18534705686654e-04f);
    q = fmaf(x2, q, 2.26843463243900e-03f);
    q = fmaf(x2, q, 4.89352518554385e-03f);
    float r = p / q;
    return (ax < 0.0004f) ? ax : r;
}

// ---- kernel 1: V = tanh_xla(3*(E[idx] @ W.T + b)) in f32, XLA order ----
__global__ __launch_bounds__(256) void k_embed(
    const int* __restrict__ gidx,
    const float* __restrict__ E1, const float* __restrict__ E2,
    const float* __restrict__ W1, const float* __restrict__ b1,
    const float* __restrict__ W2, const float* __restrict__ b2,
    float* __restrict__ V1, float* __restrict__ V2)
{
    __shared__ float W1s[DIM][DIM + 1];
    __shared__ float W2s[DIM][DIM + 1];
    __shared__ float E1s[4][DIM];
    __shared__ float E2s[4][DIM];
    const int t = threadIdx.x;
    for (int i = t; i < DIM * DIM; i += 256) {
        W1s[i >> 6][i & 63] = W1[i];
        W2s[i >> 6][i & 63] = W2[i];
    }
    const int rbase = blockIdx.x * 4;
    for (int i = t; i < 4 * DIM; i += 256) {
        const int r = i >> 6, k = i & 63;
        const int g = gidx[rbase + r];
        E1s[r][k] = E1[(size_t)g * DIM + k];
        E2s[r][k] = E2[(size_t)g * DIM + k];
    }
    __syncthreads();
    const int o = t & 63, rs = t >> 6;
    float m1 = 0.0f, m2 = 0.0f;
    #pragma unroll
    for (int k = 0; k < DIM; ++k) {
        m1 = fmaf(E1s[rs][k], W1s[o][k], m1);
        m2 = fmaf(E2s[rs][k], W2s[o][k], m2);
    }
    V1[(size_t)(rbase + rs) * DIM + o] = tanh_xla(3.0f * (m1 + b1[o]));
    V2[(size_t)(rbase + rs) * DIM + o] = tanh_xla(3.0f * (m2 + b2[o]));
}

// ---- kernel 2: A = relu(tanh_xla(3*(M1 - M2))), bit-exact XLA chains. ----
// 1D triangular grid; BK2=16 -> 32 KB LDS. NO min-waves bound: the 128
// accumulators need ~124 VGPR + AGPR overflow; clamping to 64 spills 8 GB
// to scratch (round-7 regression: FETCH 19MB->2.6GB, 220->1635 us).
__global__ __launch_bounds__(256) void k_score(
    const float* __restrict__ V1, const float* __restrict__ V2,
    float* __restrict__ out)
{
    // decode upper-tri linear id -> (bi, bj), bi <= bj
    const int L = blockIdx.x;
    int bi = (int)(64.5f - sqrtf(fmaf(-2.0f, (float)L, 64.5f * 64.5f)));
    while (bi * NTB - (bi * (bi - 1)) / 2 > L) --bi;
    while ((bi + 1) * NTB - ((bi + 1) * bi) / 2 <= L) ++bi;
    const int bj = bi + (L - (bi * NTB - (bi * (bi - 1)) / 2));

    __shared__ float sA1[BK2][TILE];           // V1 rows I, k-major
    __shared__ float sA2[BK2][TILE];           // V2 rows I
    __shared__ float sB1[BK2][TILE];           // V1 rows J
    __shared__ float sB2[BK2][TILE];           // V2 rows J

    const int t = threadIdx.x;
    const int tx = t & 15;                     // 8 cols each
    const int ty = t >> 4;                     // 8 rows each
    const int Ibase = bi * TILE, Jbase = bj * TILE;

    float acc1[8][8], acc2[8][8];
    #pragma unroll
    for (int i = 0; i < 8; ++i)
        #pragma unroll
        for (int j = 0; j < 8; ++j) { acc1[i][j] = 0.0f; acc2[i][j] = 0.0f; }

    for (int ck = 0; ck < DIM; ck += BK2) {    // ascending k chunks
        __syncthreads();
        #pragma unroll
        for (int it = 0; it < 2; ++it) {       // stage transposed, r = lane-fast
            const int idx = it * 256 + t;      // 0..511
            const int r   = idx & 127;
            const int c4  = idx >> 7;          // 0..3
            float4 f;
            f = *(const float4*)&V1[(size_t)(Ibase + r) * DIM + ck + c4 * 4];
            sA1[c4*4+0][r]=f.x; sA1[c4*4+1][r]=f.y; sA1[c4*4+2][r]=f.z; sA1[c4*4+3][r]=f.w;
            f = *(const float4*)&V2[(size_t)(Ibase + r) * DIM + ck + c4 * 4];
            sA2[c4*4+0][r]=f.x; sA2[c4*4+1][r]=f.y; sA2[c4*4+2][r]=f.z; sA2[c4*4+3][r]=f.w;
            f = *(const float4*)&V1[(size_t)(Jbase + r) * DIM + ck + c4 * 4];
            sB1[c4*4+0][r]=f.x; sB1[c4*4+1][r]=f.y; sB1[c4*4+2][r]=f.z; sB1[c4*4+3][r]=f.w;
            f = *(const float4*)&V2[(size_t)(Jbase + r) * DIM + ck + c4 * 4];
            sB2[c4*4+0][r]=f.x; sB2[c4*4+1][r]=f.y; sB2[c4*4+2][r]=f.z; sB2[c4*4+3][r]=f.w;
        }
        __syncthreads();
        #pragma unroll 2
        for (int k = 0; k < BK2; ++k) {        // strictly ascending k
            float a1[8], a2[8], c1[8], c2[8];
            *(float4*)&a1[0] = *(const float4*)&sA1[k][ty * 8];
            *(float4*)&a1[4] = *(const float4*)&sA1[k][ty * 8 + 4];
            *(float4*)&a2[0] = *(const float4*)&sA2[k][ty * 8];
            *(float4*)&a2[4] = *(const float4*)&sA2[k][ty * 8 + 4];
            *(float4*)&c1[0] = *(const float4*)&sB1[k][tx * 8];
            *(float4*)&c1[4] = *(const float4*)&sB1[k][tx * 8 + 4];
            *(float4*)&c2[0] = *(const float4*)&sB2[k][tx * 8];
            *(float4*)&c2[4] = *(const float4*)&sB2[k][tx * 8 + 4];
            #pragma unroll
            for (int i = 0; i < 8; ++i)
                #pragma unroll
                for (int j = 0; j < 8; ++j) {
                    acc1[i][j] = fmaf(a1[i], c2[j], acc1[i][j]);  // M1: v1_i.v2_j
                    acc2[i][j] = fmaf(a2[i], c1[j], acc2[i][j]);  // M2: v2_i.v1_j
                }
        }
    }
    // epilogue in-place: acc1 <- wn (normal), acc2 <- wm (mirror)
    #pragma unroll
    for (int i = 0; i < 8; ++i)
        #pragma unroll
        for (int j = 0; j < 8; ++j) {
            const float aa = acc1[i][j] - acc2[i][j];   // one f32 sub (M1-M2)
            const float tt = tanh_xla_pos(3.0f * fabsf(aa));
            acc1[i][j] = (aa > 0.0f) ? tt : 0.0f;       // relu(tanh(3a))
            acc2[i][j] = (aa < 0.0f) ? tt : 0.0f;       // relu(tanh(-3a))
        }
    #pragma unroll
    for (int i = 0; i < 8; ++i) {
        const int gi = Ibase + ty * 8 + i;
        float4* p = (float4*)&out[(size_t)gi * NN + Jbase + tx * 8];
        p[0] = make_float4(acc1[i][0], acc1[i][1], acc1[i][2], acc1[i][3]);
        p[1] = make_float4(acc1[i][4], acc1[i][5], acc1[i][6], acc1[i][7]);
    }
    if (bi != bj) {
        #pragma unroll
        for (int j = 0; j < 8; ++j) {
            const int gj = Jbase + tx * 8 + j;
            float4* p = (float4*)&out[(size_t)gj * NN + Ibase + ty * 8];
            p[0] = make_float4(acc2[0][j], acc2[1][j], acc2[2][j], acc2[3][j]);
            p[1] = make_float4(acc2[4][j], acc2[5][j], acc2[6][j], acc2[7][j]);
        }
    }
}

// ---- kernel 3: exact stable top-32 per row, 44-bit radix select ----
// key = (A_bits << 13) | (8191 - col). Uniform early-break when resolved.
__global__ __launch_bounds__(256) void k_topk(float* __restrict__ out)
{
    __shared__ uint32_t hist[4][2048];
    __shared__ uint32_t waveTot[4];
    __shared__ uint32_t bc_bin, bc_ca, bc_m, bc_flag;

    const int row = blockIdx.x;
    const int t = threadIdx.x;
    const int wid = t >> 6, lane = t & 63;
    float* rp = out + (size_t)row * NN;

    float v[32];
    #pragma unroll
    for (int s = 0; s < 8; ++s) {
        const float4 f = *(const float4*)&rp[(s * 256 + t) * 4];
        v[s*4+0] = f.x; v[s*4+1] = f.y; v[s*4+2] = f.z; v[s*4+3] = f.w;
    }
    if (t == 0) bc_flag = 0;

    uint64_t prefix = 0, thr = 0;
    int need = KSEL;
    bool done = false;   // block-uniform at all times

    for (int pass = 0; pass < 4; ++pass) {
        const int shift = 33 - 11 * pass;
        {   // zero hist: 2048 uint4 / 256 thr = 8 each
            const uint4 z = make_uint4(0u, 0u, 0u, 0u);
            uint4* hp = (uint4*)hist;
            #pragma unroll
            for (int i = 0; i < 8; ++i) hp[i * 256 + t] = z;
        }
        __syncthreads();
        #pragma unroll
        for (int s = 0; s < 8; ++s) {
            #pragma unroll
            for (int e = 0; e < 4; ++e) {
                const uint32_t vb = __float_as_uint(v[s*4+e]);
                if (vb == 0u) continue;
                const int gi = s * 1024 + t * 4 + e;
                const uint64_t key = ((uint64_t)vb << 13) | (uint32_t)(8191 - gi);
                if ((key >> (shift + 11)) == prefix)
                    atomicAdd(&hist[wid][(uint32_t)((key >> shift) & 2047u)], 1u);
            }
        }
        __syncthreads();
        uint32_t m[8]; uint32_t tot = 0;
        #pragma unroll
        for (int i = 0; i < 8; ++i) {
            const int b = t * 8 + i;
            m[i] = hist[0][b] + hist[1][b] + hist[2][b] + hist[3][b];
            tot += m[i];
        }
        uint32_t ssum = tot;   // inclusive suffix-sum within wave
        #pragma unroll
        for (int d = 1; d < 64; d <<= 1) {
            const uint32_t o = __shfl_down(ssum, d, 64);
            if (lane + d < 64) ssum += o;
        }
        if (lane == 0) waveTot[wid] = ssum;
        __syncthreads();
        {
            uint32_t above = 0;
            for (int w2 = wid + 1; w2 < 4; ++w2) above += waveTot[w2];
            if (pass == 0) {
                const uint32_t totalAll = waveTot[0] + waveTot[1] + waveTot[2] + waveTot[3];
                if (totalAll < (uint32_t)need && t == 0) bc_flag = 1;  // <32 positives
            }
            uint32_t c = (ssum - tot) + above;       // count in bins above my chunk
            #pragma unroll
            for (int i = 7; i >= 0; --i) {           // walk my 8 bins top-down
                if (c < (uint32_t)need && (uint32_t)need <= c + m[i]) {
                    bc_bin = (uint32_t)(t * 8 + i);  // unique winner
                    bc_ca  = c;
                    bc_m   = m[i];
                }
                c += m[i];
            }
        }
        __syncthreads();
        if (bc_flag) { thr = 1; done = true; }       // keep all positives
        else {
            prefix = (prefix << 11) | (uint64_t)bc_bin;
            need  -= (int)bc_ca;
            if ((uint32_t)need == bc_m) {            // whole bin selected exactly
                thr = prefix << shift;               // bin lower bound
                done = true;
            } else if (pass == 3) { thr = prefix; done = true; }
        }
        if (done) break;                              // block-uniform
        __syncthreads();
    }

    #pragma unroll
    for (int s = 0; s < 8; ++s) {
        float w[4];
        #pragma unroll
        for (int e = 0; e < 4; ++e) {
            const float a = v[s*4+e];
            const uint32_t vb = __float_as_uint(a);
            const int gi = s * 1024 + t * 4 + e;
            const uint64_t key = ((uint64_t)vb << 13) | (uint32_t)(8191 - gi);
            w[e] = (vb != 0u && key >= thr) ? a : 0.f;
        }
        *(float4*)&rp[(s * 256 + t) * 4] = make_float4(w[0], w[1], w[2], w[3]);
    }
}

extern "C" void kernel_launch(void* const* d_in, const int* in_sizes, int n_in,
                              void* d_out, int out_size, void* d_ws, size_t ws_size,
                              hipStream_t stream)
{
    const int*   idx = (const int*)  d_in[0];
    const float* E1  = (const float*)d_in[1];
    const float* E2  = (const float*)d_in[2];
    const float* W1  = (const float*)d_in[3];
    const float* b1  = (const float*)d_in[4];
    const float* W2  = (const float*)d_in[5];
    const float* b2  = (const float*)d_in[6];
    float* out = (float*)d_out;
    float* V1 = (float*)d_ws;                 // 2 MB
    float* V2 = V1 + (size_t)NN * DIM;        // 2 MB

    k_embed<<<NN / 4, 256, 0, stream>>>(idx, E1, E2, W1, b1, W2, b2, V1, V2);
    k_score<<<NTRI, 256, 0, stream>>>(V1, V2, out);
    k_topk<<<NN, 256, 0, stream>>>(out);
}

// Round 9
// 298.832 us; speedup vs baseline: 5.9246x; 1.0067x over previous
//
#include <hip/hip_runtime.h>
#include <stdint.h>
#include <math.h>

#define NN 8192
#define DIM 64
#define KSEL 32
#define BK2 16
#define TILE 128
#define NTB (NN / TILE)          // 64 tiles per side
#define NTRI ((NTB * (NTB + 1)) / 2)   // 2080 upper-tri blocks

// ---- XLA/Eigen f32 tanh rational approximation (bit-exact emulation) ----
__device__ __forceinline__ float tanh_xla(float x) {
    const float kClamp = 7.90531110763549805f;
    float xc = fminf(fmaxf(x, -kClamp), kClamp);
    float x2 = xc * xc;
    float p = -2.76076847742355e-16f;
    p = fmaf(x2, p, 2.00018790482477e-13f);
    p = fmaf(x2, p, -8.60467152213735e-11f);
    p = fmaf(x2, p, 5.12229709037114e-08f);
    p = fmaf(x2, p, 1.48572235717979e-05f);
    p = fmaf(x2, p, 6.37261928875436e-04f);
    p = fmaf(x2, p, 4.89352455891786e-03f);
    p = xc * p;
    float q = 1.19825839466702e-06f;
    q = fmaf(x2, q, 1.18534705686654e-04f);
    q = fmaf(x2, q, 2.26843463243900e-03f);
    q = fmaf(x2, q, 4.89352518554385e-03f);
    float r = p / q;
    return (fabsf(x) < 0.0004f) ? x : r;
}
// positive-input variant (ax >= 0), same bits as tanh_xla(ax)
__device__ __forceinline__ float tanh_xla_pos(float ax) {
    const float kClamp = 7.90531110763549805f;
    float xc = fminf(ax, kClamp);
    float x2 = xc * xc;
    float p = -2.76076847742355e-16f;
    p = fmaf(x2, p, 2.00018790482477e-13f);
    p = fmaf(x2, p, -8.60467152213735e-11f);
    p = fmaf(x2, p, 5.12229709037114e-08f);
    p = fmaf(x2, p, 1.48572235717979e-05f);
    p = fmaf(x2, p, 6.37261928875436e-04f);
    p = fmaf(x2, p, 4.89352455891786e-03f);
    p = xc * p;
    float q = 1.19825839466702e-06f;
    q = fmaf(x2, q, 1.18534705686654e-04f);
    q = fmaf(x2, q, 2.26843463243900e-03f);
    q = fmaf(x2, q, 4.89352518554385e-03f);
    float r = p / q;
    return (ax < 0.0004f) ? ax : r;
}

// ---- kernel 1: V = tanh_xla(3*(E[idx] @ W.T + b)) in f32, XLA order ----
__global__ __launch_bounds__(256) void k_embed(
    const int* __restrict__ gidx,
    const float* __restrict__ E1, const float* __restrict__ E2,
    const float* __restrict__ W1, const float* __restrict__ b1,
    const float* __restrict__ W2, const float* __restrict__ b2,
    float* __restrict__ V1, float* __restrict__ V2)
{
    __shared__ float W1s[DIM][DIM + 1];
    __shared__ float W2s[DIM][DIM + 1];
    __shared__ float E1s[4][DIM];
    __shared__ float E2s[4][DIM];
    const int t = threadIdx.x;
    for (int i = t; i < DIM * DIM; i += 256) {
        W1s[i >> 6][i & 63] = W1[i];
        W2s[i >> 6][i & 63] = W2[i];
    }
    const int rbase = blockIdx.x * 4;
    for (int i = t; i < 4 * DIM; i += 256) {
        const int r = i >> 6, k = i & 63;
        const int g = gidx[rbase + r];
        E1s[r][k] = E1[(size_t)g * DIM + k];
        E2s[r][k] = E2[(size_t)g * DIM + k];
    }
    __syncthreads();
    const int o = t & 63, rs = t >> 6;
    float m1 = 0.0f, m2 = 0.0f;
    #pragma unroll
    for (int k = 0; k < DIM; ++k) {
        m1 = fmaf(E1s[rs][k], W1s[o][k], m1);
        m2 = fmaf(E2s[rs][k], W2s[o][k], m2);
    }
    V1[(size_t)(rbase + rs) * DIM + o] = tanh_xla(3.0f * (m1 + b1[o]));
    V2[(size_t)(rbase + rs) * DIM + o] = tanh_xla(3.0f * (m2 + b2[o]));
}

// ---- kernel 2: A = relu(tanh_xla(3*(M1 - M2))), bit-exact XLA chains. ----
// Thread owns cols {tx*4..+3} u {64+tx*4..+3}: B-side ds_read_b128 is 16
// lanes at 16B stride = 256B contiguous -> 2 lanes/bank = conflict-FREE
// (old tx*8 mapping was 32B stride -> 4-way conflict, 8.5M extra cycles).
__global__ __launch_bounds__(256) void k_score(
    const float* __restrict__ V1, const float* __restrict__ V2,
    float* __restrict__ out)
{
    // decode upper-tri linear id -> (bi, bj), bi <= bj
    const int L = blockIdx.x;
    int bi = (int)(64.5f - sqrtf(fmaf(-2.0f, (float)L, 64.5f * 64.5f)));
    while (bi * NTB - (bi * (bi - 1)) / 2 > L) --bi;
    while ((bi + 1) * NTB - ((bi + 1) * bi) / 2 <= L) ++bi;
    const int bj = bi + (L - (bi * NTB - (bi * (bi - 1)) / 2));

    __shared__ float sA1[BK2][TILE];           // V1 rows I, k-major
    __shared__ float sA2[BK2][TILE];           // V2 rows I
    __shared__ float sB1[BK2][TILE];           // V1 rows J
    __shared__ float sB2[BK2][TILE];           // V2 rows J

    const int t = threadIdx.x;
    const int tx = t & 15;                     // col groups: tx*4 and 64+tx*4
    const int ty = t >> 4;                     // 8 rows each: ty*8..+7
    const int Ibase = bi * TILE, Jbase = bj * TILE;

    float acc1[8][8], acc2[8][8];
    #pragma unroll
    for (int i = 0; i < 8; ++i)
        #pragma unroll
        for (int j = 0; j < 8; ++j) { acc1[i][j] = 0.0f; acc2[i][j] = 0.0f; }

    for (int ck = 0; ck < DIM; ck += BK2) {    // ascending k chunks
        __syncthreads();
        #pragma unroll
        for (int it = 0; it < 2; ++it) {       // stage transposed, r = lane-fast
            const int idx = it * 256 + t;      // 0..511
            const int r   = idx & 127;
            const int c4  = idx >> 7;          // 0..3
            float4 f;
            f = *(const float4*)&V1[(size_t)(Ibase + r) * DIM + ck + c4 * 4];
            sA1[c4*4+0][r]=f.x; sA1[c4*4+1][r]=f.y; sA1[c4*4+2][r]=f.z; sA1[c4*4+3][r]=f.w;
            f = *(const float4*)&V2[(size_t)(Ibase + r) * DIM + ck + c4 * 4];
            sA2[c4*4+0][r]=f.x; sA2[c4*4+1][r]=f.y; sA2[c4*4+2][r]=f.z; sA2[c4*4+3][r]=f.w;
            f = *(const float4*)&V1[(size_t)(Jbase + r) * DIM + ck + c4 * 4];
            sB1[c4*4+0][r]=f.x; sB1[c4*4+1][r]=f.y; sB1[c4*4+2][r]=f.z; sB1[c4*4+3][r]=f.w;
            f = *(const float4*)&V2[(size_t)(Jbase + r) * DIM + ck + c4 * 4];
            sB2[c4*4+0][r]=f.x; sB2[c4*4+1][r]=f.y; sB2[c4*4+2][r]=f.z; sB2[c4*4+3][r]=f.w;
        }
        __syncthreads();
        #pragma unroll 2
        for (int k = 0; k < BK2; ++k) {        // strictly ascending k
            float a1[8], a2[8], c1[8], c2[8];
            *(float4*)&a1[0] = *(const float4*)&sA1[k][ty * 8];
            *(float4*)&a1[4] = *(const float4*)&sA1[k][ty * 8 + 4];
            *(float4*)&a2[0] = *(const float4*)&sA2[k][ty * 8];
            *(float4*)&a2[4] = *(const float4*)&sA2[k][ty * 8 + 4];
            *(float4*)&c1[0] = *(const float4*)&sB1[k][tx * 4];
            *(float4*)&c1[4] = *(const float4*)&sB1[k][tx * 4 + 64];
            *(float4*)&c2[0] = *(const float4*)&sB2[k][tx * 4];
            *(float4*)&c2[4] = *(const float4*)&sB2[k][tx * 4 + 64];
            #pragma unroll
            for (int i = 0; i < 8; ++i)
                #pragma unroll
                for (int j = 0; j < 8; ++j) {
                    acc1[i][j] = fmaf(a1[i], c2[j], acc1[i][j]);  // M1: v1_i.v2_j
                    acc2[i][j] = fmaf(a2[i], c1[j], acc2[i][j]);  // M2: v2_i.v1_j
                }
        }
    }
    // epilogue in-place: acc1 <- wn (normal), acc2 <- wm (mirror)
    #pragma unroll
    for (int i = 0; i < 8; ++i)
        #pragma unroll
        for (int j = 0; j < 8; ++j) {
            const float aa = acc1[i][j] - acc2[i][j];   // one f32 sub (M1-M2)
            const float tt = tanh_xla_pos(3.0f * fabsf(aa));
            acc1[i][j] = (aa > 0.0f) ? tt : 0.0f;       // relu(tanh(3a))
            acc2[i][j] = (aa < 0.0f) ? tt : 0.0f;       // relu(tanh(-3a))
        }
    #pragma unroll
    for (int i = 0; i < 8; ++i) {
        const int gi = Ibase + ty * 8 + i;
        *(float4*)&out[(size_t)gi * NN + Jbase + tx * 4] =
            make_float4(acc1[i][0], acc1[i][1], acc1[i][2], acc1[i][3]);
        *(float4*)&out[(size_t)gi * NN + Jbase + 64 + tx * 4] =
            make_float4(acc1[i][4], acc1[i][5], acc1[i][6], acc1[i][7]);
    }
    if (bi != bj) {
        #pragma unroll
        for (int j = 0; j < 8; ++j) {
            const int gj = Jbase + tx * 4 + (j >> 2) * 64 + (j & 3);
            float4* p = (float4*)&out[(size_t)gj * NN + Ibase + ty * 8];
            p[0] = make_float4(acc2[0][j], acc2[1][j], acc2[2][j], acc2[3][j]);
            p[1] = make_float4(acc2[4][j], acc2[5][j], acc2[6][j], acc2[7][j]);
        }
    }
}

// ---- kernel 3: exact stable top-32 per row, 44-bit radix select ----
// key = (A_bits << 13) | (8191 - col). Uniform early-break when resolved.
__global__ __launch_bounds__(256) void k_topk(float* __restrict__ out)
{
    __shared__ uint32_t hist[4][2048];
    __shared__ uint32_t waveTot[4];
    __shared__ uint32_t bc_bin, bc_ca, bc_m, bc_flag;

    const int row = blockIdx.x;
    const int t = threadIdx.x;
    const int wid = t >> 6, lane = t & 63;
    float* rp = out + (size_t)row * NN;

    float v[32];
    #pragma unroll
    for (int s = 0; s < 8; ++s) {
        const float4 f = *(const float4*)&rp[(s * 256 + t) * 4];
        v[s*4+0] = f.x; v[s*4+1] = f.y; v[s*4+2] = f.z; v[s*4+3] = f.w;
    }
    if (t == 0) bc_flag = 0;

    uint64_t prefix = 0, thr = 0;
    int need = KSEL;
    bool done = false;   // block-uniform at all times

    for (int pass = 0; pass < 4; ++pass) {
        const int shift = 33 - 11 * pass;
        {   // zero hist: 2048 uint4 / 256 thr = 8 each
            const uint4 z = make_uint4(0u, 0u, 0u, 0u);
            uint4* hp = (uint4*)hist;
            #pragma unroll
            for (int i = 0; i < 8; ++i) hp[i * 256 + t] = z;
        }
        __syncthreads();
        #pragma unroll
        for (int s = 0; s < 8; ++s) {
            #pragma unroll
            for (int e = 0; e < 4; ++e) {
                const uint32_t vb = __float_as_uint(v[s*4+e]);
                if (vb == 0u) continue;
                const int gi = s * 1024 + t * 4 + e;
                const uint64_t key = ((uint64_t)vb << 13) | (uint32_t)(8191 - gi);
                if ((key >> (shift + 11)) == prefix)
                    atomicAdd(&hist[wid][(uint32_t)((key >> shift) & 2047u)], 1u);
            }
        }
        __syncthreads();
        uint32_t m[8]; uint32_t tot = 0;
        #pragma unroll
        for (int i = 0; i < 8; ++i) {
            const int b = t * 8 + i;
            m[i] = hist[0][b] + hist[1][b] + hist[2][b] + hist[3][b];
            tot += m[i];
        }
        uint32_t ssum = tot;   // inclusive suffix-sum within wave
        #pragma unroll
        for (int d = 1; d < 64; d <<= 1) {
            const uint32_t o = __shfl_down(ssum, d, 64);
            if (lane + d < 64) ssum += o;
        }
        if (lane == 0) waveTot[wid] = ssum;
        __syncthreads();
        {
            uint32_t above = 0;
            for (int w2 = wid + 1; w2 < 4; ++w2) above += waveTot[w2];
            if (pass == 0) {
                const uint32_t totalAll = waveTot[0] + waveTot[1] + waveTot[2] + waveTot[3];
                if (totalAll < (uint32_t)need && t == 0) bc_flag = 1;  // <32 positives
            }
            uint32_t c = (ssum - tot) + above;       // count in bins above my chunk
            #pragma unroll
            for (int i = 7; i >= 0; --i) {           // walk my 8 bins top-down
                if (c < (uint32_t)need && (uint32_t)need <= c + m[i]) {
                    bc_bin = (uint32_t)(t * 8 + i);  // unique winner
                    bc_ca  = c;
                    bc_m   = m[i];
                }
                c += m[i];
            }
        }
        __syncthreads();
        if (bc_flag) { thr = 1; done = true; }       // keep all positives
        else {
            prefix = (prefix << 11) | (uint64_t)bc_bin;
            need  -= (int)bc_ca;
            if ((uint32_t)need == bc_m) {            // whole bin selected exactly
                thr = prefix << shift;               // bin lower bound
                done = true;
            } else if (pass == 3) { thr = prefix; done = true; }
        }
        if (done) break;                              // block-uniform
        __syncthreads();
    }

    #pragma unroll
    for (int s = 0; s < 8; ++s) {
        float w[4];
        #pragma unroll
        for (int e = 0; e < 4; ++e) {
            const float a = v[s*4+e];
            const uint32_t vb = __float_as_uint(a);
            const int gi = s * 1024 + t * 4 + e;
            const uint64_t key = ((uint64_t)vb << 13) | (uint32_t)(8191 - gi);
            w[e] = (vb != 0u && key >= thr) ? a : 0.f;
        }
        *(float4*)&rp[(s * 256 + t) * 4] = make_float4(w[0], w[1], w[2], w[3]);
    }
}

extern "C" void kernel_launch(void* const* d_in, const int* in_sizes, int n_in,
                              void* d_out, int out_size, void* d_ws, size_t ws_size,
                              hipStream_t stream)
{
    const int*   idx = (const int*)  d_in[0];
    const float* E1  = (const float*)d_in[1];
    const float* E2  = (const float*)d_in[2];
    const float* W1  = (const float*)d_in[3];
    const float* b1  = (const float*)d_in[4];
    const float* W2  = (const float*)d_in[5];
    const float* b2  = (const float*)d_in[6];
    float* out = (float*)d_out;
    float* V1 = (float*)d_ws;                 // 2 MB
    float* V2 = V1 + (size_t)NN * DIM;        // 2 MB

    k_embed<<<NN / 4, 256, 0, stream>>>(idx, E1, E2, W1, b1, W2, b2, V1, V2);
    k_score<<<NTRI, 256, 0, stream>>>(V1, V2, out);
    k_topk<<<NN, 256, 0, stream>>>(out);
}

// Round 10
// 281.362 us; speedup vs baseline: 6.2925x; 1.0621x over previous
//
#include <hip/hip_runtime.h>
#include <stdint.h>
#include <math.h>

#define NN 8192
#define DIM 64
#define KSEL 32
#define BK2 16
#define TILE 128
#define NTB (NN / TILE)          // 64 tiles per side
#define NTRI ((NTB * (NTB + 1)) / 2)   // 2080 upper-tri blocks

#define AS1 __attribute__((address_space(1)))
#define AS3 __attribute__((address_space(3)))
typedef float v2f __attribute__((ext_vector_type(2)));

// packed IEEE fma (v_pk_fma_f32) — bit-identical to two scalar fmaf
__device__ __forceinline__ v2f pk_fma(v2f a, v2f b, v2f c) {
#if __has_builtin(__builtin_elementwise_fma)
    return __builtin_elementwise_fma(a, b, c);
#else
    v2f r; r.x = fmaf(a.x, b.x, c.x); r.y = fmaf(a.y, b.y, c.y); return r;
#endif
}

// ---- XLA/Eigen f32 tanh rational approximation (bit-exact emulation) ----
__device__ __forceinline__ float tanh_xla(float x) {
    const float kClamp = 7.90531110763549805f;
    float xc = fminf(fmaxf(x, -kClamp), kClamp);
    float x2 = xc * xc;
    float p = -2.76076847742355e-16f;
    p = fmaf(x2, p, 2.00018790482477e-13f);
    p = fmaf(x2, p, -8.60467152213735e-11f);
    p = fmaf(x2, p, 5.12229709037114e-08f);
    p = fmaf(x2, p, 1.48572235717979e-05f);
    p = fmaf(x2, p, 6.37261928875436e-04f);
    p = fmaf(x2, p, 4.89352455891786e-03f);
    p = xc * p;
    float q = 1.19825839466702e-06f;
    q = fmaf(x2, q, 1.18534705686654e-04f);
    q = fmaf(x2, q, 2.26843463243900e-03f);
    q = fmaf(x2, q, 4.89352518554385e-03f);
    float r = p / q;
    return (fabsf(x) < 0.0004f) ? x : r;
}
// positive-input variant (ax >= 0), same bits as tanh_xla(ax)
__device__ __forceinline__ float tanh_xla_pos(float ax) {
    const float kClamp = 7.90531110763549805f;
    float xc = fminf(ax, kClamp);
    float x2 = xc * xc;
    float p = -2.76076847742355e-16f;
    p = fmaf(x2, p, 2.00018790482477e-13f);
    p = fmaf(x2, p, -8.60467152213735e-11f);
    p = fmaf(x2, p, 5.12229709037114e-08f);
    p = fmaf(x2, p, 1.48572235717979e-05f);
    p = fmaf(x2, p, 6.37261928875436e-04f);
    p = fmaf(x2, p, 4.89352455891786e-03f);
    p = xc * p;
    float q = 1.19825839466702e-06f;
    q = fmaf(x2, q, 1.18534705686654e-04f);
    q = fmaf(x2, q, 2.26843463243900e-03f);
    q = fmaf(x2, q, 4.89352518554385e-03f);
    float r = p / q;
    return (ax < 0.0004f) ? ax : r;
}

// ---- kernel 1: VT[o][node] = tanh_xla(3*(E[idx] @ W.T + b)), k-major out ----
__global__ __launch_bounds__(256) void k_embed(
    const int* __restrict__ gidx,
    const float* __restrict__ E1, const float* __restrict__ E2,
    const float* __restrict__ W1, const float* __restrict__ b1,
    const float* __restrict__ W2, const float* __restrict__ b2,
    float* __restrict__ VT1, float* __restrict__ VT2)
{
    __shared__ float W1s[DIM][DIM + 1];
    __shared__ float W2s[DIM][DIM + 1];
    __shared__ float E1s[4][DIM];
    __shared__ float E2s[4][DIM];
    __shared__ float T1[DIM][5];
    __shared__ float T2[DIM][5];
    const int t = threadIdx.x;
    for (int i = t; i < DIM * DIM; i += 256) {
        W1s[i >> 6][i & 63] = W1[i];
        W2s[i >> 6][i & 63] = W2[i];
    }
    const int rbase = blockIdx.x * 4;
    for (int i = t; i < 4 * DIM; i += 256) {
        const int r = i >> 6, k = i & 63;
        const int g = gidx[rbase + r];
        E1s[r][k] = E1[(size_t)g * DIM + k];
        E2s[r][k] = E2[(size_t)g * DIM + k];
    }
    __syncthreads();
    const int o = t & 63, rs = t >> 6;
    float m1 = 0.0f, m2 = 0.0f;
    #pragma unroll
    for (int k = 0; k < DIM; ++k) {
        m1 = fmaf(E1s[rs][k], W1s[o][k], m1);
        m2 = fmaf(E2s[rs][k], W2s[o][k], m2);
    }
    T1[o][rs] = tanh_xla(3.0f * (m1 + b1[o]));
    T2[o][rs] = tanh_xla(3.0f * (m2 + b2[o]));
    __syncthreads();
    const int oo = t >> 2, rr = t & 3;       // coalesced-ish 16B transposed store
    VT1[(size_t)oo * NN + rbase + rr] = T1[oo][rr];
    VT2[(size_t)oo * NN + rbase + rr] = T2[oo][rr];
}

// ---- kernel 2: A = relu(tanh_xla(3*(M1 - M2))), bit-exact XLA chains. ----
// VT k-major input -> linear global_load_lds staging, double-buffered
// (1 barrier/chunk); v_pk_fma_f32 packed accumulation (2 IEEE FMA/instr).
__global__ __launch_bounds__(256) void k_score(
    const float* __restrict__ VT1, const float* __restrict__ VT2,
    float* __restrict__ out)
{
    // decode upper-tri linear id -> (bi, bj), bi <= bj
    const int L = blockIdx.x;
    int bi = (int)(64.5f - sqrtf(fmaf(-2.0f, (float)L, 64.5f * 64.5f)));
    while (bi * NTB - (bi * (bi - 1)) / 2 > L) --bi;
    while ((bi + 1) * NTB - ((bi + 1) * bi) / 2 <= L) ++bi;
    const int bj = bi + (L - (bi * NTB - (bi * (bi - 1)) / 2));

    // [buf][array][k][col]; arrays: 0=A1(V1,I) 1=A2(V2,I) 2=B1(V1,J) 3=B2(V2,J)
    __shared__ __align__(16) float lds[2][4][BK2][TILE];   // 64 KB

    const int t = threadIdx.x;
    const int tx = t & 15;                     // col groups: tx*4 and 64+tx*4
    const int ty = t >> 4;                     // 8 rows each: ty*8..+7
    const int Ibase = bi * TILE, Jbase = bj * TILE;

    // staging role: wave w fills array w; lane l covers 16B at l*16 per 1KB chunk
    const int w = t >> 6, l = t & 63;
    const float* vt = (w & 1) ? VT2 : VT1;
    const int cbase = (w & 2) ? Jbase : Ibase;
    const int srow = (l >> 5);                 // 0/1
    const int scol = (l & 31) * 4;

    v2f acc1[8][4], acc2[8][4];
    #pragma unroll
    for (int i = 0; i < 8; ++i)
        #pragma unroll
        for (int j = 0; j < 4; ++j) { acc1[i][j] = (v2f)(0.0f); acc2[i][j] = (v2f)(0.0f); }

    // prologue fill buf0 with ck=0
    #pragma unroll
    for (int p = 0; p < 8; ++p) {
        const float* src = vt + (size_t)(2 * p + srow) * NN + cbase + scol;
        __builtin_amdgcn_global_load_lds((AS1 const void*)src,
                                         (AS3 void*)&lds[0][w][2 * p + srow][scol], 16, 0, 0);
    }
    __syncthreads();

    for (int c4 = 0; c4 < 4; ++c4) {           // ascending 16-wide k chunks
        const int cur = c4 & 1;
        if (c4 < 3) {                          // prefetch next chunk into other buf
            const int ckn = (c4 + 1) * BK2;
            #pragma unroll
            for (int p = 0; p < 8; ++p) {
                const float* src = vt + (size_t)(ckn + 2 * p + srow) * NN + cbase + scol;
                __builtin_amdgcn_global_load_lds((AS1 const void*)src,
                                                 (AS3 void*)&lds[cur ^ 1][w][2 * p + srow][scol], 16, 0, 0);
            }
        }
        #pragma unroll 2
        for (int k = 0; k < BK2; ++k) {        // strictly ascending k
            const float4 fa1l = *(const float4*)&lds[cur][0][k][ty * 8];
            const float4 fa1h = *(const float4*)&lds[cur][0][k][ty * 8 + 4];
            const float4 fa2l = *(const float4*)&lds[cur][1][k][ty * 8];
            const float4 fa2h = *(const float4*)&lds[cur][1][k][ty * 8 + 4];
            const float4 fb1l = *(const float4*)&lds[cur][2][k][tx * 4];
            const float4 fb1h = *(const float4*)&lds[cur][2][k][tx * 4 + 64];
            const float4 fb2l = *(const float4*)&lds[cur][3][k][tx * 4];
            const float4 fb2h = *(const float4*)&lds[cur][3][k][tx * 4 + 64];
            v2f c1p[4], c2p[4];
            c1p[0] = (v2f){fb1l.x, fb1l.y}; c1p[1] = (v2f){fb1l.z, fb1l.w};
            c1p[2] = (v2f){fb1h.x, fb1h.y}; c1p[3] = (v2f){fb1h.z, fb1h.w};
            c2p[0] = (v2f){fb2l.x, fb2l.y}; c2p[1] = (v2f){fb2l.z, fb2l.w};
            c2p[2] = (v2f){fb2h.x, fb2h.y}; c2p[3] = (v2f){fb2h.z, fb2h.w};
            float a1[8] = {fa1l.x, fa1l.y, fa1l.z, fa1l.w, fa1h.x, fa1h.y, fa1h.z, fa1h.w};
            float a2[8] = {fa2l.x, fa2l.y, fa2l.z, fa2l.w, fa2h.x, fa2h.y, fa2h.z, fa2h.w};
            #pragma unroll
            for (int i = 0; i < 8; ++i) {
                const v2f a1v = (v2f){a1[i], a1[i]};
                const v2f a2v = (v2f){a2[i], a2[i]};
                #pragma unroll
                for (int jp = 0; jp < 4; ++jp) {
                    acc1[i][jp] = pk_fma(a1v, c2p[jp], acc1[i][jp]);  // M1: v1_i.v2_j
                    acc2[i][jp] = pk_fma(a2v, c1p[jp], acc2[i][jp]);  // M2: v2_i.v1_j
                }
            }
        }
        __syncthreads();                       // next buf ready; cur free to refill
    }

    // epilogue: wn (normal tile), wm (mirror tile)
    float wn[8][8], wm[8][8];
    #pragma unroll
    for (int i = 0; i < 8; ++i)
        #pragma unroll
        for (int jp = 0; jp < 4; ++jp)
            #pragma unroll
            for (int e = 0; e < 2; ++e) {
                const int j = jp * 2 + e;
                const float aa = acc1[i][jp][e] - acc2[i][jp][e];  // one f32 sub
                const float tt = tanh_xla_pos(3.0f * fabsf(aa));
                wn[i][j] = (aa > 0.0f) ? tt : 0.0f;                // relu(tanh(3a))
                wm[i][j] = (aa < 0.0f) ? tt : 0.0f;                // relu(tanh(-3a))
            }
    #pragma unroll
    for (int i = 0; i < 8; ++i) {
        const int gi = Ibase + ty * 8 + i;
        *(float4*)&out[(size_t)gi * NN + Jbase + tx * 4] =
            make_float4(wn[i][0], wn[i][1], wn[i][2], wn[i][3]);
        *(float4*)&out[(size_t)gi * NN + Jbase + 64 + tx * 4] =
            make_float4(wn[i][4], wn[i][5], wn[i][6], wn[i][7]);
    }
    if (bi != bj) {
        #pragma unroll
        for (int j = 0; j < 8; ++j) {
            const int gj = Jbase + tx * 4 + (j >> 2) * 64 + (j & 3);
            float4* p = (float4*)&out[(size_t)gj * NN + Ibase + ty * 8];
            p[0] = make_float4(wm[0][j], wm[1][j], wm[2][j], wm[3][j]);
            p[1] = make_float4(wm[4][j], wm[5][j], wm[6][j], wm[7][j]);
        }
    }
}

// ---- kernel 3: exact stable top-32 per row, 44-bit radix select ----
// key = (A_bits << 13) | (8191 - col). Uniform early-break when resolved.
__global__ __launch_bounds__(256) void k_topk(float* __restrict__ out)
{
    __shared__ uint32_t hist[4][2048];
    __shared__ uint32_t waveTot[4];
    __shared__ uint32_t bc_bin, bc_ca, bc_m, bc_flag;

    const int row = blockIdx.x;
    const int t = threadIdx.x;
    const int wid = t >> 6, lane = t & 63;
    float* rp = out + (size_t)row * NN;

    float v[32];
    #pragma unroll
    for (int s = 0; s < 8; ++s) {
        const float4 f = *(const float4*)&rp[(s * 256 + t) * 4];
        v[s*4+0] = f.x; v[s*4+1] = f.y; v[s*4+2] = f.z; v[s*4+3] = f.w;
    }
    if (t == 0) bc_flag = 0;

    uint64_t prefix = 0, thr = 0;
    int need = KSEL;
    bool done = false;   // block-uniform at all times

    for (int pass = 0; pass < 4; ++pass) {
        const int shift = 33 - 11 * pass;
        {   // zero hist: 2048 uint4 / 256 thr = 8 each
            const uint4 z = make_uint4(0u, 0u, 0u, 0u);
            uint4* hp = (uint4*)hist;
            #pragma unroll
            for (int i = 0; i < 8; ++i) hp[i * 256 + t] = z;
        }
        __syncthreads();
        #pragma unroll
        for (int s = 0; s < 8; ++s) {
            #pragma unroll
            for (int e = 0; e < 4; ++e) {
                const uint32_t vb = __float_as_uint(v[s*4+e]);
                if (vb == 0u) continue;
                const int gi = s * 1024 + t * 4 + e;
                const uint64_t key = ((uint64_t)vb << 13) | (uint32_t)(8191 - gi);
                if ((key >> (shift + 11)) == prefix)
                    atomicAdd(&hist[wid][(uint32_t)((key >> shift) & 2047u)], 1u);
            }
        }
        __syncthreads();
        uint32_t m[8]; uint32_t tot = 0;
        #pragma unroll
        for (int i = 0; i < 8; ++i) {
            const int b = t * 8 + i;
            m[i] = hist[0][b] + hist[1][b] + hist[2][b] + hist[3][b];
            tot += m[i];
        }
        uint32_t ssum = tot;   // inclusive suffix-sum within wave
        #pragma unroll
        for (int d = 1; d < 64; d <<= 1) {
            const uint32_t o = __shfl_down(ssum, d, 64);
            if (lane + d < 64) ssum += o;
        }
        if (lane == 0) waveTot[wid] = ssum;
        __syncthreads();
        {
            uint32_t above = 0;
            for (int w2 = wid + 1; w2 < 4; ++w2) above += waveTot[w2];
            if (pass == 0) {
                const uint32_t totalAll = waveTot[0] + waveTot[1] + waveTot[2] + waveTot[3];
                if (totalAll < (uint32_t)need && t == 0) bc_flag = 1;  // <32 positives
            }
            uint32_t c = (ssum - tot) + above;       // count in bins above my chunk
            #pragma unroll
            for (int i = 7; i >= 0; --i) {           // walk my 8 bins top-down
                if (c < (uint32_t)need && (uint32_t)need <= c + m[i]) {
                    bc_bin = (uint32_t)(t * 8 + i);  // unique winner
                    bc_ca  = c;
                    bc_m   = m[i];
                }
                c += m[i];
            }
        }
        __syncthreads();
        if (bc_flag) { thr = 1; done = true; }       // keep all positives
        else {
            prefix = (prefix << 11) | (uint64_t)bc_bin;
            need  -= (int)bc_ca;
            if ((uint32_t)need == bc_m) {            // whole bin selected exactly
                thr = prefix << shift;               // bin lower bound
                done = true;
            } else if (pass == 3) { thr = prefix; done = true; }
        }
        if (done) break;                              // block-uniform
        __syncthreads();
    }

    #pragma unroll
    for (int s = 0; s < 8; ++s) {
        float w[4];
        #pragma unroll
        for (int e = 0; e < 4; ++e) {
            const float a = v[s*4+e];
            const uint32_t vb = __float_as_uint(a);
            const int gi = s * 1024 + t * 4 + e;
            const uint64_t key = ((uint64_t)vb << 13) | (uint32_t)(8191 - gi);
            w[e] = (vb != 0u && key >= thr) ? a : 0.f;
        }
        *(float4*)&rp[(s * 256 + t) * 4] = make_float4(w[0], w[1], w[2], w[3]);
    }
}

extern "C" void kernel_launch(void* const* d_in, const int* in_sizes, int n_in,
                              void* d_out, int out_size, void* d_ws, size_t ws_size,
                              hipStream_t stream)
{
    const int*   idx = (const int*)  d_in[0];
    const float* E1  = (const float*)d_in[1];
    const float* E2  = (const float*)d_in[2];
    const float* W1  = (const float*)d_in[3];
    const float* b1  = (const float*)d_in[4];
    const float* W2  = (const float*)d_in[5];
    const float* b2  = (const float*)d_in[6];
    float* out = (float*)d_out;
    float* VT1 = (float*)d_ws;                 // 2 MB, [64][8192] k-major
    float* VT2 = VT1 + (size_t)NN * DIM;       // 2 MB

    k_embed<<<NN / 4, 256, 0, stream>>>(idx, E1, E2, W1, b1, W2, b2, VT1, VT2);
    k_score<<<NTRI, 256, 0, stream>>>(VT1, VT2, out);
    k_topk<<<NN, 256, 0, stream>>>(out);
}